// Round 5
// baseline (266.187 us; speedup 1.0000x reference)
//
#include <hip/hip_runtime.h>
#include <hip/hip_fp16.h>
#include <math.h>

// TemporalMotor: per-sample keyframe interpolation.
//   inputs : t (N,), translations (64,3), quaternions (64,4), keyframe_times (64,)
//   outputs: trans (N,3) then quat (N,4), concatenated flat in d_out (float32)
//
// Roofline: ~33.5 MB read + ~235 MB write => ~41 us @ 6.5 TB/s (fill-demonstrated).
// R2 levers: f16-packed 3-gather LDS records (48B/elem), nontemporal streams,
// wave-staged trans so ALL output bytes leave as aligned dwordx4 NT stores.

#define KFR   64
#define NSEG  63
#define BLOCK 256
#define CHUNK 1024   // elements per block-iteration (256 threads * 4)

typedef float v4f __attribute__((ext_vector_type(4)));

static __device__ __forceinline__ float pack2h(float a, float b) {
    __half2 h = __floats2half2_rn(a, b);      // low = a, high = b
    unsigned int u;
    __builtin_memcpy(&u, &h, 4);
    return __uint_as_float(u);
}
static __device__ __forceinline__ float2 unpack2h(float p) {
    unsigned int u = __float_as_uint(p);
    __half2 h;
    __builtin_memcpy(&h, &u, 4);
    return __half22float2(h);                 // .x = low, .y = high
}

__global__ __launch_bounds__(BLOCK) void temporal_motor_kernel(
    const float* __restrict__ t_in,
    const float* __restrict__ translations,
    const float* __restrict__ quaternions,
    const float* __restrict__ keyframe_times,
    float* __restrict__ out_trans,
    float* __restrict__ out_quat,
    int nchunks)
{
    // Per-segment records (s = 0..62), one float4 each:
    //   sA[s] = (t_prev, t_next, 1/(dt+1e-8), half2(theta, 1-d))
    //   sT[s] = (h2(px,py), h2(pz,dx), h2(dy,dz), inv_sin_theta)   0 marks nlerp
    //   sQ[s] = (h2(q0x,q0y), h2(q0z,q0w), h2(q1x,q1y), h2(q1z,q1w))
    __shared__ float4 sA[KFR];
    __shared__ float4 sT[KFR];
    __shared__ float4 sQ[KFR];
    __shared__ __align__(16) float sStage[BLOCK / 64][192];  // 768B per wave

    const int tid = threadIdx.x;
    if (tid < NSEG) {
        const int s = tid;
        float t0 = keyframe_times[s];
        float t1 = keyframe_times[s + 1];

        float ax = quaternions[4 * s + 0], ay = quaternions[4 * s + 1];
        float az = quaternions[4 * s + 2], aw = quaternions[4 * s + 3];
        float bx = quaternions[4 * s + 4], by = quaternions[4 * s + 5];
        float bz = quaternions[4 * s + 6], bw = quaternions[4 * s + 7];
        float ia = 1.0f / fmaxf(sqrtf(ax * ax + ay * ay + az * az + aw * aw), 1e-12f);
        float ib = 1.0f / fmaxf(sqrtf(bx * bx + by * by + bz * bz + bw * bw), 1e-12f);
        ax *= ia; ay *= ia; az *= ia; aw *= ia;
        bx *= ib; by *= ib; bz *= ib; bw *= ib;

        float d0 = ax * bx + ay * by + az * bz + aw * bw;
        float sgn = (d0 < 0.0f) ? -1.0f : 1.0f;            // shortest arc
        bx *= sgn; by *= sgn; bz *= sgn; bw *= sgn;
        float d = fminf(fabsf(d0), 1.0f);                  // clip(|dot|, -1, 1)

        float theta  = acosf(d);
        float st     = sqrtf(fmaxf(1.0f - d * d, 0.0f));
        float inv_st = (d > 0.9995f) ? 0.0f : (1.0f / st); // 0 => nlerp segment

        float px = translations[3 * s + 0], py = translations[3 * s + 1];
        float pz = translations[3 * s + 2];
        float dx = translations[3 * s + 3] - px;
        float dy = translations[3 * s + 4] - py;
        float dz = translations[3 * s + 5] - pz;

        sA[s] = make_float4(t0, t1, 1.0f / (t1 - t0 + 1e-8f), pack2h(theta, 1.0f - d));
        sT[s] = make_float4(pack2h(px, py), pack2h(pz, dx), pack2h(dy, dz), inv_st);
        sQ[s] = make_float4(pack2h(ax, ay), pack2h(az, aw), pack2h(bx, by), pack2h(bz, bw));
    }
    __syncthreads();

    const int lane = tid & 63;
    const int wave = tid >> 6;
    float* stg = sStage[wave];

    for (int chunk = blockIdx.x; chunk < nchunks; chunk += gridDim.x) {
        const int base = chunk * CHUNK + wave * 256 + lane;

        #pragma unroll
        for (int j = 0; j < 4; ++j) {
            const int idx = base + j * 64;    // lane-contiguous per instruction
            const float tt = __builtin_nontemporal_load(t_in + idx);

            // --- searchsorted-left (clipped): arithmetic guess + exact fixup ---
            int s = (int)ceilf(tt * (float)NSEG) - 1;
            s = (s < 0) ? 0 : (s > NSEG - 1) ? NSEG - 1 : s;
            float4 a = sA[s];
            while (s > 0 && a.x >= tt)        { --s; a = sA[s]; }
            while (s < NSEG - 1 && a.y < tt)  { ++s; a = sA[s]; }

            const float lt  = (tt - a.x) * a.z;
            const float omt = 1.0f - lt;
            const float2 thd = unpack2h(a.w);         // x = theta, y = 1-d

            const float4 tv   = sT[s];
            const float2 pxy  = unpack2h(tv.x);       // px, py
            const float2 pzdx = unpack2h(tv.y);       // pz, dx
            const float2 dydz = unpack2h(tv.z);       // dy, dz
            const float inv_st = tv.w;

            // --- slerp weights via identity; nlerp fallback; branch-free ---
            float sn, cs;
            __sincosf(lt * thd.x, &sn, &cs);
            const float wbs = sn * inv_st;                    // sin(lt*th)/sin(th)
            const float was = fmaf(thd.y, wbs, cs - wbs);     // cs - d*wbs

            const float s2  = fmaf(-2.0f * lt * omt, thd.y, 1.0f);  // |nlerp|^2
            const float inv = rsqrtf(fmaxf(s2, 1e-24f));
            const bool  fb  = (inv_st == 0.0f);
            const float wa  = fb ? omt * inv : was;
            const float wb  = fb ? lt * inv  : wbs;

            const float4 qv  = sQ[s];
            const float2 q0a = unpack2h(qv.x), q0b = unpack2h(qv.y);
            const float2 q1a = unpack2h(qv.z), q1b = unpack2h(qv.w);
            v4f oq;
            oq.x = wa * q0a.x + wb * q1a.x;
            oq.y = wa * q0a.y + wb * q1a.y;
            oq.z = wa * q0b.x + wb * q1b.x;
            oq.w = wa * q0b.y + wb * q1b.y;

            // --- trans into per-wave stage (stride-3 writes: bank permutation) ---
            stg[lane * 3 + 0] = fmaf(lt, pzdx.y, pxy.x);
            stg[lane * 3 + 1] = fmaf(lt, dydz.x, pxy.y);
            stg[lane * 3 + 2] = fmaf(lt, dydz.y, pzdx.x);

            __builtin_nontemporal_store(oq, (v4f*)out_quat + idx);   // 1KB/wave-inst

            // --- flush stage: 48 lanes x aligned dwordx4 NT (768B contiguous) ---
            const int g = idx - lane;   // wave-group base element
            if (lane < 48) {
                v4f v = ((v4f*)stg)[lane];
                __builtin_nontemporal_store(v, (v4f*)(out_trans + (size_t)g * 3) + lane);
            }
        }
    }
}

// Scalar fallback (tail elements, or K != 64 / unaligned N).
__global__ void temporal_motor_tail(
    const float* __restrict__ t_in,
    const float* __restrict__ translations,
    const float* __restrict__ quaternions,
    const float* __restrict__ keyframe_times,
    float* __restrict__ out_trans,
    float* __restrict__ out_quat,
    int n_start, int n, int K)
{
    int i = n_start + blockIdx.x * blockDim.x + threadIdx.x;
    if (i >= n) return;
    float tt = t_in[i];

    int g = 1;
    while (g < K - 1 && keyframe_times[g] < tt) ++g;
    float tpw = keyframe_times[g - 1], tnw = keyframe_times[g];
    float lt = (tt - tpw) / (tnw - tpw + 1e-8f);
    float omt = 1.0f - lt;

    for (int c = 0; c < 3; ++c)
        out_trans[3 * (size_t)i + c] =
            omt * translations[3 * (g - 1) + c] + lt * translations[3 * g + c];

    float q0[4], q1[4];
    float n0 = 0, n1 = 0;
    for (int c = 0; c < 4; ++c) { q0[c] = quaternions[4 * (g - 1) + c]; n0 += q0[c] * q0[c]; }
    for (int c = 0; c < 4; ++c) { q1[c] = quaternions[4 * g + c];       n1 += q1[c] * q1[c]; }
    float i0 = 1.0f / fmaxf(sqrtf(n0), 1e-12f), i1 = 1.0f / fmaxf(sqrtf(n1), 1e-12f);
    float d = 0;
    for (int c = 0; c < 4; ++c) { q0[c] *= i0; q1[c] *= i1; }
    for (int c = 0; c < 4; ++c) d += q0[c] * q1[c];
    float sgn = (d < 0.0f) ? -1.0f : 1.0f;
    for (int c = 0; c < 4; ++c) q1[c] *= sgn;
    d = fminf(fabsf(d), 1.0f);
    float theta = acosf(d);
    float st = sqrtf(fmaxf(1.0f - d * d, 0.0f));
    float invst = (st < 1e-8f) ? 1.0f : (1.0f / st);
    float s0 = __sinf(omt * theta) * invst, s1 = __sinf(lt * theta) * invst;
    float l[4], ln = 0;
    for (int c = 0; c < 4; ++c) { l[c] = q0[c] + lt * (q1[c] - q0[c]); ln += l[c] * l[c]; }
    float li = 1.0f / fmaxf(sqrtf(ln), 1e-12f);
    bool fb = (d > 0.9995f);
    for (int c = 0; c < 4; ++c)
        out_quat[4 * (size_t)i + c] = fb ? l[c] * li : (s0 * q0[c] + s1 * q1[c]);
}

extern "C" void kernel_launch(void* const* d_in, const int* in_sizes, int n_in,
                              void* d_out, int out_size, void* d_ws, size_t ws_size,
                              hipStream_t stream) {
    const float* t_in  = (const float*)d_in[0];
    const float* trans = (const float*)d_in[1];
    const float* quats = (const float*)d_in[2];
    const float* ktime = (const float*)d_in[3];
    const int N = in_sizes[0];
    const int K = in_sizes[3];

    float* out_trans = (float*)d_out;
    float* out_quat  = (float*)d_out + (size_t)N * 3;

    // fast path needs K==64 and N%4==0 (16B-aligned quat stream)
    if (K == KFR && (N & 3) == 0) {
        const int nchunks = N / CHUNK;
        if (nchunks > 0) {
            int blocks = nchunks < 2048 ? nchunks : 2048;  // grid-stride
            temporal_motor_kernel<<<blocks, BLOCK, 0, stream>>>(
                t_in, trans, quats, ktime, out_trans, out_quat, nchunks);
        }
        const int rem_start = nchunks * CHUNK;
        if (rem_start < N) {
            int rem = N - rem_start;
            temporal_motor_tail<<<(rem + 63) / 64, 64, 0, stream>>>(
                t_in, trans, quats, ktime, out_trans, out_quat, rem_start, N, K);
        }
    } else {
        temporal_motor_tail<<<(N + 255) / 256, 256, 0, stream>>>(
            t_in, trans, quats, ktime, out_trans, out_quat, 0, N, K);
    }
}

// Round 7
// 264.514 us; speedup vs baseline: 1.0063x; 1.0063x over previous
//
#include <hip/hip_runtime.h>
#include <hip/hip_fp16.h>
#include <math.h>

// TemporalMotor: per-sample keyframe interpolation.
//   inputs : t (N,), translations (64,3), quaternions (64,4), keyframe_times (64,)
//   outputs: trans (N,3) then quat (N,4), concatenated flat in d_out (float32)
//
// R5 model: bench dur = poison-fill(143us) + restore(~10us) + kernel.
// Kernel floor ~80us (235MB writes + ~250MB deferred poison evictions + 34MB reads).
// R5 lever: MLP. 8 elem/thread, all loads issued before compute, no LDS store
// staging (L2 write-back merges dwordx3 streams), no exec-mask partial stores.

#define KFR   64
#define NSEG  63
#define BLOCK 256
#define EPT   8                    // elements per thread
#define CHUNK (BLOCK * EPT)        // 2048 elements per block-chunk

typedef float v4f __attribute__((ext_vector_type(4)));
typedef float v3f __attribute__((ext_vector_type(3)));

static __device__ __forceinline__ float pack2h(float a, float b) {
    __half2 h = __floats2half2_rn(a, b);      // low = a, high = b
    unsigned int u;
    __builtin_memcpy(&u, &h, 4);
    return __uint_as_float(u);
}
static __device__ __forceinline__ float2 unpack2h(float p) {
    unsigned int u = __float_as_uint(p);
    __half2 h;
    __builtin_memcpy(&h, &u, 4);
    return __half22float2(h);                 // .x = low, .y = high
}

__global__ __launch_bounds__(BLOCK) void temporal_motor_kernel(
    const float* __restrict__ t_in,
    const float* __restrict__ translations,
    const float* __restrict__ quaternions,
    const float* __restrict__ keyframe_times,
    float* __restrict__ out_trans,
    float* __restrict__ out_quat,
    int nchunks)
{
    // Per-segment records (s = 0..62), one float4 each:
    //   sA[s] = (t_prev, t_next, 1/(dt+1e-8), half2(theta, 1-d))
    //   sT[s] = (h2(px,py), h2(pz,dx), h2(dy,dz), inv_sin_theta)   0 marks nlerp
    //   sQ[s] = (h2(q0x,q0y), h2(q0z,q0w), h2(q1x,q1y), h2(q1z,q1w))
    __shared__ float4 sA[KFR];
    __shared__ float4 sT[KFR];
    __shared__ float4 sQ[KFR];

    const int tid = threadIdx.x;
    if (tid < NSEG) {
        const int s = tid;
        float t0 = keyframe_times[s];
        float t1 = keyframe_times[s + 1];

        float ax = quaternions[4 * s + 0], ay = quaternions[4 * s + 1];
        float az = quaternions[4 * s + 2], aw = quaternions[4 * s + 3];
        float bx = quaternions[4 * s + 4], by = quaternions[4 * s + 5];
        float bz = quaternions[4 * s + 6], bw = quaternions[4 * s + 7];
        float ia = 1.0f / fmaxf(sqrtf(ax * ax + ay * ay + az * az + aw * aw), 1e-12f);
        float ib = 1.0f / fmaxf(sqrtf(bx * bx + by * by + bz * bz + bw * bw), 1e-12f);
        ax *= ia; ay *= ia; az *= ia; aw *= ia;
        bx *= ib; by *= ib; bz *= ib; bw *= ib;

        float d0 = ax * bx + ay * by + az * bz + aw * bw;
        float sgn = (d0 < 0.0f) ? -1.0f : 1.0f;            // shortest arc
        bx *= sgn; by *= sgn; bz *= sgn; bw *= sgn;
        float d = fminf(fabsf(d0), 1.0f);                  // clip(|dot|, -1, 1)

        float theta  = acosf(d);
        float st     = sqrtf(fmaxf(1.0f - d * d, 0.0f));
        float inv_st = (d > 0.9995f) ? 0.0f : (1.0f / st); // 0 => nlerp segment

        float px = translations[3 * s + 0], py = translations[3 * s + 1];
        float pz = translations[3 * s + 2];
        float dx = translations[3 * s + 3] - px;
        float dy = translations[3 * s + 4] - py;
        float dz = translations[3 * s + 5] - pz;

        sA[s] = make_float4(t0, t1, 1.0f / (t1 - t0 + 1e-8f), pack2h(theta, 1.0f - d));
        sT[s] = make_float4(pack2h(px, py), pack2h(pz, dx), pack2h(dy, dz), inv_st);
        sQ[s] = make_float4(pack2h(ax, ay), pack2h(az, aw), pack2h(bx, by), pack2h(bz, bw));
    }
    __syncthreads();

    const int lane = tid & 63;
    const int wave = tid >> 6;

    for (int chunk = blockIdx.x; chunk < nchunks; chunk += gridDim.x) {
        // wave w owns 512 consecutive elements; within the wave, stride-64 so
        // every load/store instruction is lane-contiguous (perfect coalescing).
        const int base = chunk * CHUNK + wave * (EPT * 64) + lane;

        // ---- phase 1: issue ALL loads (8 independent, static-indexed) ----
        float tt[EPT];
        #pragma unroll
        for (int j = 0; j < EPT; ++j)
            tt[j] = t_in[base + j * 64];

        // ---- phase 2: compute + store ----
        #pragma unroll
        for (int j = 0; j < EPT; ++j) {
            const int idx = base + j * 64;
            const float t = tt[j];

            // searchsorted-left (clipped): arithmetic guess + exact fixup
            int s = (int)ceilf(t * (float)NSEG) - 1;
            s = (s < 0) ? 0 : (s > NSEG - 1) ? NSEG - 1 : s;
            float4 a = sA[s];
            while (s > 0 && a.x >= t)        { --s; a = sA[s]; }
            while (s < NSEG - 1 && a.y < t)  { ++s; a = sA[s]; }

            const float lt  = (t - a.x) * a.z;
            const float omt = 1.0f - lt;
            const float2 thd = unpack2h(a.w);         // x = theta, y = 1-d

            const float4 tv   = sT[s];
            const float2 pxy  = unpack2h(tv.x);       // px, py
            const float2 pzdx = unpack2h(tv.y);       // pz, dx
            const float2 dydz = unpack2h(tv.z);       // dy, dz
            const float inv_st = tv.w;

            // slerp weights via identity; nlerp fallback; branch-free
            float sn, cs;
            __sincosf(lt * thd.x, &sn, &cs);
            const float wbs = sn * inv_st;                    // sin(lt*th)/sin(th)
            const float was = fmaf(thd.y, wbs, cs - wbs);     // cs - d*wbs

            const float s2  = fmaf(-2.0f * lt * omt, thd.y, 1.0f);  // |nlerp|^2
            const float inv = rsqrtf(fmaxf(s2, 1e-24f));
            const bool  fb  = (inv_st == 0.0f);
            const float wa  = fb ? omt * inv : was;
            const float wb  = fb ? lt * inv  : wbs;

            const float4 qv  = sQ[s];
            const float2 q0a = unpack2h(qv.x), q0b = unpack2h(qv.y);
            const float2 q1a = unpack2h(qv.z), q1b = unpack2h(qv.w);
            v4f oq;
            oq.x = wa * q0a.x + wb * q1a.x;
            oq.y = wa * q0a.y + wb * q1a.y;
            oq.z = wa * q0b.x + wb * q1b.x;
            oq.w = wa * q0b.y + wb * q1b.y;

            v3f tr;
            tr.x = fmaf(lt, pzdx.y, pxy.x);
            tr.y = fmaf(lt, dydz.x, pxy.y);
            tr.z = fmaf(lt, dydz.y, pzdx.x);

            // dense per-lane NT stores; L2 write-back merges the x3 stream
            __builtin_nontemporal_store(oq, (v4f*)out_quat + idx);
            __builtin_nontemporal_store(tr, (v3f*)(out_trans + (size_t)idx * 3));
        }
    }
}

// Scalar fallback (tail elements, or K != 64 / unaligned N).
__global__ void temporal_motor_tail(
    const float* __restrict__ t_in,
    const float* __restrict__ translations,
    const float* __restrict__ quaternions,
    const float* __restrict__ keyframe_times,
    float* __restrict__ out_trans,
    float* __restrict__ out_quat,
    int n_start, int n, int K)
{
    int i = n_start + blockIdx.x * blockDim.x + threadIdx.x;
    if (i >= n) return;
    float tt = t_in[i];

    int g = 1;
    while (g < K - 1 && keyframe_times[g] < tt) ++g;
    float tpw = keyframe_times[g - 1], tnw = keyframe_times[g];
    float lt = (tt - tpw) / (tnw - tpw + 1e-8f);
    float omt = 1.0f - lt;

    for (int c = 0; c < 3; ++c)
        out_trans[3 * (size_t)i + c] =
            omt * translations[3 * (g - 1) + c] + lt * translations[3 * g + c];

    float q0[4], q1[4];
    float n0 = 0, n1 = 0;
    for (int c = 0; c < 4; ++c) { q0[c] = quaternions[4 * (g - 1) + c]; n0 += q0[c] * q0[c]; }
    for (int c = 0; c < 4; ++c) { q1[c] = quaternions[4 * g + c];       n1 += q1[c] * q1[c]; }
    float i0 = 1.0f / fmaxf(sqrtf(n0), 1e-12f), i1 = 1.0f / fmaxf(sqrtf(n1), 1e-12f);
    float d = 0;
    for (int c = 0; c < 4; ++c) { q0[c] *= i0; q1[c] *= i1; }
    for (int c = 0; c < 4; ++c) d += q0[c] * q1[c];
    float sgn = (d < 0.0f) ? -1.0f : 1.0f;
    for (int c = 0; c < 4; ++c) q1[c] *= sgn;
    d = fminf(fabsf(d), 1.0f);
    float theta = acosf(d);
    float st = sqrtf(fmaxf(1.0f - d * d, 0.0f));
    float invst = (st < 1e-8f) ? 1.0f : (1.0f / st);
    float s0 = __sinf(omt * theta) * invst, s1 = __sinf(lt * theta) * invst;
    float l[4], ln = 0;
    for (int c = 0; c < 4; ++c) { l[c] = q0[c] + lt * (q1[c] - q0[c]); ln += l[c] * l[c]; }
    float li = 1.0f / fmaxf(sqrtf(ln), 1e-12f);
    bool fb = (d > 0.9995f);
    for (int c = 0; c < 4; ++c)
        out_quat[4 * (size_t)i + c] = fb ? l[c] * li : (s0 * q0[c] + s1 * q1[c]);
}

extern "C" void kernel_launch(void* const* d_in, const int* in_sizes, int n_in,
                              void* d_out, int out_size, void* d_ws, size_t ws_size,
                              hipStream_t stream) {
    const float* t_in  = (const float*)d_in[0];
    const float* trans = (const float*)d_in[1];
    const float* quats = (const float*)d_in[2];
    const float* ktime = (const float*)d_in[3];
    const int N = in_sizes[0];
    const int K = in_sizes[3];

    float* out_trans = (float*)d_out;
    float* out_quat  = (float*)d_out + (size_t)N * 3;

    // fast path needs K==64 and N%4==0 (16B-aligned quat stream)
    if (K == KFR && (N & 3) == 0) {
        const int nchunks = N / CHUNK;
        if (nchunks > 0) {
            int blocks = nchunks < 4096 ? nchunks : 4096;  // grid-stride
            temporal_motor_kernel<<<blocks, BLOCK, 0, stream>>>(
                t_in, trans, quats, ktime, out_trans, out_quat, nchunks);
        }
        const int rem_start = nchunks * CHUNK;
        if (rem_start < N) {
            int rem = N - rem_start;
            temporal_motor_tail<<<(rem + 63) / 64, 64, 0, stream>>>(
                t_in, trans, quats, ktime, out_trans, out_quat, rem_start, N, K);
        }
    } else {
        temporal_motor_tail<<<(N + 255) / 256, 256, 0, stream>>>(
            t_in, trans, quats, ktime, out_trans, out_quat, 0, N, K);
    }
}